// Round 1
// baseline (183.458 us; speedup 1.0000x reference)
//
#include <hip/hip_runtime.h>
#include <math.h>

#define N_ROWS 262144
#define D 256
#define C 1000

// ---------------- init: zero counters/sums, min = +inf ----------------
__global__ void k_init(int* __restrict__ cnt, float* __restrict__ sums,
                       unsigned int* __restrict__ minb) {
    int i = blockIdx.x * 256 + threadIdx.x;
    if (i < C) cnt[i] = 0;
    if (i < C * D) sums[i] = 0.f;
    if (i == 0) *minb = 0x7f800000u;  // +inf
}

// ---------------- rank within class ----------------
__global__ void k_rank(const int* __restrict__ labels, int* __restrict__ cnt,
                       int* __restrict__ rank) {
    int i = blockIdx.x * 256 + threadIdx.x;
    if (i < N_ROWS) rank[i] = atomicAdd(&cnt[labels[i]], 1);
}

// ---------------- exclusive prefix sum over counts (1 block, 1024 thr) ----------------
__global__ void k_scan(const int* __restrict__ cnt, int* __restrict__ offs) {
    __shared__ int s[1024];
    int t = threadIdx.x;
    int v = (t < C) ? cnt[t] : 0;
    s[t] = v;
    __syncthreads();
    for (int off = 1; off < 1024; off <<= 1) {
        int x = (t >= off) ? s[t - off] : 0;
        __syncthreads();
        s[t] += x;
        __syncthreads();
    }
    if (t < C) offs[t] = s[t] - v;
}

// ---------------- scatter row indices into class-sorted order ----------------
__global__ void k_scatter(const int* __restrict__ labels, const int* __restrict__ rank,
                          const int* __restrict__ offs, int* __restrict__ sidx) {
    int i = blockIdx.x * 256 + threadIdx.x;
    if (i < N_ROWS) sidx[offs[labels[i]] + rank[i]] = i;
}

// ---------------- per-class sum: 1 block per class, float4 gather ----------------
__global__ __launch_bounds__(256) void k_classsum(
    const float* __restrict__ feat, const int* __restrict__ sidx,
    const int* __restrict__ offs, const int* __restrict__ cnt,
    float* __restrict__ sums) {
    int c = blockIdx.x;
    int tid = threadIdx.x;
    int sub = tid >> 6;   // which row of a 4-row batch (== wave id)
    int cg  = tid & 63;   // column group (4 floats each)
    int start = offs[c];
    int n = cnt[c];

    float4 acc = make_float4(0.f, 0.f, 0.f, 0.f);
    int r = sub;
    // 4 outstanding loads per thread for latency hiding
    for (; r + 12 < n; r += 16) {
        int row0 = sidx[start + r];
        int row1 = sidx[start + r + 4];
        int row2 = sidx[start + r + 8];
        int row3 = sidx[start + r + 12];
        float4 v0 = *reinterpret_cast<const float4*>(feat + (size_t)row0 * D + cg * 4);
        float4 v1 = *reinterpret_cast<const float4*>(feat + (size_t)row1 * D + cg * 4);
        float4 v2 = *reinterpret_cast<const float4*>(feat + (size_t)row2 * D + cg * 4);
        float4 v3 = *reinterpret_cast<const float4*>(feat + (size_t)row3 * D + cg * 4);
        acc.x += v0.x + v1.x + v2.x + v3.x;
        acc.y += v0.y + v1.y + v2.y + v3.y;
        acc.z += v0.z + v1.z + v2.z + v3.z;
        acc.w += v0.w + v1.w + v2.w + v3.w;
    }
    for (; r < n; r += 4) {
        int row = sidx[start + r];
        float4 v = *reinterpret_cast<const float4*>(feat + (size_t)row * D + cg * 4);
        acc.x += v.x; acc.y += v.y; acc.z += v.z; acc.w += v.w;
    }

    __shared__ float4 part[4][64];
    part[sub][cg] = acc;
    __syncthreads();
    if (sub == 0) {
        float4 a = part[0][cg], b = part[1][cg], c2 = part[2][cg], d2 = part[3][cg];
        float4 o;
        o.x = a.x + b.x + c2.x + d2.x;
        o.y = a.y + b.y + c2.y + d2.y;
        o.z = a.z + b.z + c2.z + d2.z;
        o.w = a.w + b.w + c2.w + d2.w;
        *reinterpret_cast<float4*>(sums + (size_t)c * D + cg * 4) = o;
    }
}

// ---------------- normalize centroids: mn = mean / ||mean|| ----------------
__global__ __launch_bounds__(256) void k_norm(
    const float* __restrict__ sums, const int* __restrict__ cnt,
    float* __restrict__ mn) {
    int c = blockIdx.x, t = threadIdx.x;
    float cn = fmaxf((float)cnt[c], 1.0f);
    float mean = sums[c * D + t] / cn;
    float ss = mean * mean;
    for (int o = 32; o; o >>= 1) ss += __shfl_down(ss, o, 64);
    __shared__ float w[4];
    if ((t & 63) == 0) w[t >> 6] = ss;
    __syncthreads();
    float tot = w[0] + w[1] + w[2] + w[3];
    float norm = sqrtf(tot);
    mn[c * D + t] = mean / norm;
}

// ---------------- min off-diagonal cosine distance ----------------
// 32x32 pair tiles, XOR-swizzled LDS (conflict-free ds_read_b128), 2x2 reg blocking
__global__ __launch_bounds__(256) void k_mindist(
    const float* __restrict__ mn, unsigned int* __restrict__ minb) {
    constexpr int T = 32;
    int bi = blockIdx.x >> 5, bj = blockIdx.x & 31;
    int i0 = bi * T, j0 = bj * T;
    __shared__ float A[T * D];
    __shared__ float B[T * D];
    int tid = threadIdx.x;

    for (int k = tid; k < T * D; k += 256) {
        int r = k >> 8, d = k & 255;
        int sw = d ^ (((r >> 1) & 7) << 2);
        int gi = i0 + r, gj = j0 + r;
        A[r * D + sw] = (gi < C) ? mn[(size_t)gi * D + d] : 0.f;
        B[r * D + sw] = (gj < C) ? mn[(size_t)gj * D + d] : 0.f;
    }
    __syncthreads();

    int ti = tid >> 4, tj = tid & 15;
    int il = ti * 2, jl = tj * 2;
    int sa = (ti & 7) << 2;
    int sb = (tj & 7) << 2;

    float a00 = 0.f, a01 = 0.f, a10 = 0.f, a11 = 0.f;
    #pragma unroll 4
    for (int d = 0; d < D; d += 4) {
        float4 x0 = *reinterpret_cast<const float4*>(&A[il * D + (d ^ sa)]);
        float4 x1 = *reinterpret_cast<const float4*>(&A[(il + 1) * D + (d ^ sa)]);
        float4 y0 = *reinterpret_cast<const float4*>(&B[jl * D + (d ^ sb)]);
        float4 y1 = *reinterpret_cast<const float4*>(&B[(jl + 1) * D + (d ^ sb)]);
        a00 += x0.x * y0.x + x0.y * y0.y + x0.z * y0.z + x0.w * y0.w;
        a01 += x0.x * y1.x + x0.y * y1.y + x0.z * y1.z + x0.w * y1.w;
        a10 += x1.x * y0.x + x1.y * y0.y + x1.z * y0.z + x1.w * y0.w;
        a11 += x1.x * y1.x + x1.y * y1.y + x1.z * y1.z + x1.w * y1.w;
    }

    float m = INFINITY;
    int gi0 = i0 + il, gj0 = j0 + jl;
    {
        int gi = gi0, gj = gj0;
        if (gi < C && gj < C && gi != gj)
            m = fminf(m, 1.f - fminf(fmaxf(a00, -1.f), 1.f));
    }
    {
        int gi = gi0, gj = gj0 + 1;
        if (gi < C && gj < C && gi != gj)
            m = fminf(m, 1.f - fminf(fmaxf(a01, -1.f), 1.f));
    }
    {
        int gi = gi0 + 1, gj = gj0;
        if (gi < C && gj < C && gi != gj)
            m = fminf(m, 1.f - fminf(fmaxf(a10, -1.f), 1.f));
    }
    {
        int gi = gi0 + 1, gj = gj0 + 1;
        if (gi < C && gj < C && gi != gj)
            m = fminf(m, 1.f - fminf(fmaxf(a11, -1.f), 1.f));
    }

    for (int o = 32; o; o >>= 1) m = fminf(m, __shfl_down(m, o, 64));
    if ((tid & 63) == 0) atomicMin(minb, __float_as_uint(m));
}

// ---------------- finalize ----------------
__global__ void k_final(const unsigned int* __restrict__ minb, float* __restrict__ out) {
    float d = __uint_as_float(*minb);
    out[0] = logf(1.0f / (d + 1e-6f) + 1.0f);
}

extern "C" void kernel_launch(void* const* d_in, const int* in_sizes, int n_in,
                              void* d_out, int out_size, void* d_ws, size_t ws_size,
                              hipStream_t stream) {
    const float* feat  = (const float*)d_in[0];
    const int*   labels = (const int*)d_in[1];
    // d_in[2] (conf_mat) is unused by the reference computation.
    float* out = (float*)d_out;

    int*      cnt  = (int*)d_ws;            // [1024]
    int*      offs = cnt + 1024;            // [1024]
    int*      rank = offs + 1024;           // [N_ROWS]
    int*      sidx = rank + N_ROWS;         // [N_ROWS]
    float*    sums = (float*)(sidx + N_ROWS);   // [C*D]
    float*    mnrm = sums + C * D;              // [C*D]
    unsigned* minb = (unsigned*)(mnrm + C * D); // [1]

    k_init<<<(C * D + 255) / 256, 256, 0, stream>>>(cnt, sums, minb);
    k_rank<<<(N_ROWS + 255) / 256, 256, 0, stream>>>(labels, cnt, rank);
    k_scan<<<1, 1024, 0, stream>>>(cnt, offs);
    k_scatter<<<(N_ROWS + 255) / 256, 256, 0, stream>>>(labels, rank, offs, sidx);
    k_classsum<<<C, 256, 0, stream>>>(feat, sidx, offs, cnt, sums);
    k_norm<<<C, 256, 0, stream>>>(sums, cnt, mnrm);
    k_mindist<<<32 * 32, 256, 0, stream>>>(mnrm, minb);
    k_final<<<1, 1, 0, stream>>>(minb, out);
}

// Round 2
// 158.316 us; speedup vs baseline: 1.1588x; 1.1588x over previous
//
#include <hip/hip_runtime.h>
#include <math.h>

#define N_ROWS 262144
#define D 256
#define C 1000
#define TILE 32
#define NTILE 32                      // ceil(C/TILE)
#define NPAIR (NTILE * (NTILE + 1) / 2)  // 528 triangular tile pairs

// ---------------- rank within class ----------------
__global__ void k_rank(const int* __restrict__ labels, int* __restrict__ cnt,
                       int* __restrict__ rank) {
    int i = blockIdx.x * 256 + threadIdx.x;
    if (i < N_ROWS) rank[i] = atomicAdd(&cnt[labels[i]], 1);
}

// ---------------- exclusive prefix sum over counts (1 block) + init minb/done ----------------
__global__ void k_scan(const int* __restrict__ cnt, int* __restrict__ offs,
                       unsigned int* __restrict__ minb, unsigned int* __restrict__ done) {
    __shared__ int s[1024];
    int t = threadIdx.x;
    if (t == 0) *minb = 0x7f800000u;  // +inf
    if (t == 1) *done = 0u;
    int v = (t < C) ? cnt[t] : 0;
    s[t] = v;
    __syncthreads();
    for (int off = 1; off < 1024; off <<= 1) {
        int x = (t >= off) ? s[t - off] : 0;
        __syncthreads();
        s[t] += x;
        __syncthreads();
    }
    if (t < C) offs[t] = s[t] - v;
}

// ---------------- scatter row indices into class-sorted order ----------------
__global__ void k_scatter(const int* __restrict__ labels, const int* __restrict__ rank,
                          const int* __restrict__ offs, int* __restrict__ sidx) {
    int i = blockIdx.x * 256 + threadIdx.x;
    if (i < N_ROWS) sidx[offs[labels[i]] + rank[i]] = i;
}

// ---------------- per-class sum + mean + L2-normalize, fused ----------------
// 1 block (1024 thr = 16 waves) per class. Wave w handles rows w, w+16, ...
// Each wave reads a full 1 KB row coalesced (64 lanes x float4).
__global__ __launch_bounds__(1024) void k_classsum(
    const float* __restrict__ feat, const int* __restrict__ sidx,
    const int* __restrict__ offs, const int* __restrict__ cnt,
    float* __restrict__ mn) {
    int c = blockIdx.x;
    int tid = threadIdx.x;
    int w = tid >> 6;    // wave 0..15
    int cg = tid & 63;   // column group (float4)
    int start = offs[c];
    int n = cnt[c];

    // stage row ids in LDS (expected n ~ 262; 1024 is ample)
    __shared__ int srow[1024];
    int nstage = (n < 1024) ? n : 1024;
    for (int i = tid; i < nstage; i += 1024) srow[i] = sidx[start + i];
    __syncthreads();

    float4 acc = make_float4(0.f, 0.f, 0.f, 0.f);
    int r = w;
    for (; r + 48 < nstage; r += 64) {
        int row0 = srow[r];
        int row1 = srow[r + 16];
        int row2 = srow[r + 32];
        int row3 = srow[r + 48];
        float4 v0 = *reinterpret_cast<const float4*>(feat + (size_t)row0 * D + cg * 4);
        float4 v1 = *reinterpret_cast<const float4*>(feat + (size_t)row1 * D + cg * 4);
        float4 v2 = *reinterpret_cast<const float4*>(feat + (size_t)row2 * D + cg * 4);
        float4 v3 = *reinterpret_cast<const float4*>(feat + (size_t)row3 * D + cg * 4);
        acc.x += v0.x + v1.x + v2.x + v3.x;
        acc.y += v0.y + v1.y + v2.y + v3.y;
        acc.z += v0.z + v1.z + v2.z + v3.z;
        acc.w += v0.w + v1.w + v2.w + v3.w;
    }
    for (; r < nstage; r += 16) {
        int row = srow[r];
        float4 v = *reinterpret_cast<const float4*>(feat + (size_t)row * D + cg * 4);
        acc.x += v.x; acc.y += v.y; acc.z += v.z; acc.w += v.w;
    }
    // improbable overflow tail (n > 1024 never happens for this input)
    for (r = 1024 + w; r < n; r += 16) {
        int row = sidx[start + r];
        float4 v = *reinterpret_cast<const float4*>(feat + (size_t)row * D + cg * 4);
        acc.x += v.x; acc.y += v.y; acc.z += v.z; acc.w += v.w;
    }

    __shared__ float4 part[16][64];
    part[w][cg] = acc;
    __syncthreads();
    if (w == 0) {
        float4 t = make_float4(0.f, 0.f, 0.f, 0.f);
        #pragma unroll
        for (int i = 0; i < 16; ++i) {
            float4 p = part[i][cg];
            t.x += p.x; t.y += p.y; t.z += p.z; t.w += p.w;
        }
        float inv = 1.0f / fmaxf((float)n, 1.0f);
        float4 mean = make_float4(t.x * inv, t.y * inv, t.z * inv, t.w * inv);
        float ss = mean.x * mean.x + mean.y * mean.y + mean.z * mean.z + mean.w * mean.w;
        for (int o = 32; o; o >>= 1) ss += __shfl_down(ss, o, 64);
        ss = __shfl(ss, 0, 64);
        float rn = rsqrtf(ss);
        float4 o4 = make_float4(mean.x * rn, mean.y * rn, mean.z * rn, mean.w * rn);
        reinterpret_cast<float4*>(mn + (size_t)c * D)[cg] = o4;
    }
}

// ---------------- min off-diagonal cosine distance (triangular tiles, fused final) --------
__global__ __launch_bounds__(256) void k_mindist(
    const float* __restrict__ mn, unsigned int* __restrict__ minb,
    unsigned int* __restrict__ done, float* __restrict__ out) {
    // decode triangular pair (bi <= bj), block-uniform scalar loop
    int t = blockIdx.x;
    int bi = 0;
    while (t >= NTILE - bi) { t -= NTILE - bi; ++bi; }
    int bj = bi + t;
    int i0 = bi * TILE, j0 = bj * TILE;

    __shared__ float A[TILE * D];
    __shared__ float B[TILE * D];
    float4* A4 = reinterpret_cast<float4*>(A);
    float4* B4 = reinterpret_cast<float4*>(B);
    int tid = threadIdx.x;

    // float4 staging with group-level XOR swizzle (group = float4)
    for (int k = tid; k < TILE * (D / 4); k += 256) {
        int r = k >> 6;       // row in tile
        int g = k & 63;       // float4 group
        int sg = g ^ ((r >> 1) & 7);
        int gi = i0 + r, gj = j0 + r;
        float4 z = make_float4(0.f, 0.f, 0.f, 0.f);
        A4[r * 64 + sg] = (gi < C) ? reinterpret_cast<const float4*>(mn + (size_t)gi * D)[g] : z;
        B4[r * 64 + sg] = (gj < C) ? reinterpret_cast<const float4*>(mn + (size_t)gj * D)[g] : z;
    }
    __syncthreads();

    int ti = tid >> 4, tj = tid & 15;
    int il = ti * 2, jl = tj * 2;
    int sa = ti & 7;   // == (il>>1)&7
    int sb = tj & 7;

    float a00 = 0.f, a01 = 0.f, a10 = 0.f, a11 = 0.f;
    #pragma unroll 4
    for (int g = 0; g < 64; ++g) {
        float4 x0 = A4[il * 64 + (g ^ sa)];
        float4 x1 = A4[(il + 1) * 64 + (g ^ sa)];
        float4 y0 = B4[jl * 64 + (g ^ sb)];
        float4 y1 = B4[(jl + 1) * 64 + (g ^ sb)];
        a00 += x0.x * y0.x + x0.y * y0.y + x0.z * y0.z + x0.w * y0.w;
        a01 += x0.x * y1.x + x0.y * y1.y + x0.z * y1.z + x0.w * y1.w;
        a10 += x1.x * y0.x + x1.y * y0.y + x1.z * y0.z + x1.w * y0.w;
        a11 += x1.x * y1.x + x1.y * y1.y + x1.z * y1.z + x1.w * y1.w;
    }

    float m = INFINITY;
    int gi0 = i0 + il, gj0 = j0 + jl;
    if (gi0 < C && gj0 < C && gi0 != gj0)         m = fminf(m, 1.f - fminf(fmaxf(a00, -1.f), 1.f));
    if (gi0 < C && gj0 + 1 < C && gi0 != gj0 + 1) m = fminf(m, 1.f - fminf(fmaxf(a01, -1.f), 1.f));
    if (gi0 + 1 < C && gj0 < C && gi0 + 1 != gj0) m = fminf(m, 1.f - fminf(fmaxf(a10, -1.f), 1.f));
    if (gi0 + 1 < C && gj0 + 1 < C && gi0 != gj0) m = fminf(m, 1.f - fminf(fmaxf(a11, -1.f), 1.f));

    for (int o = 32; o; o >>= 1) m = fminf(m, __shfl_down(m, o, 64));
    if ((tid & 63) == 0) atomicMin(minb, __float_as_uint(m));

    // fused finalize: last block to finish computes the loss
    __syncthreads();
    if (tid == 0) {
        __threadfence();
        unsigned int old = atomicAdd(done, 1u);
        if (old == (unsigned int)(gridDim.x - 1)) {
            float d = __uint_as_float(atomicOr(minb, 0u));
            out[0] = logf(1.0f / (d + 1e-6f) + 1.0f);
        }
    }
}

extern "C" void kernel_launch(void* const* d_in, const int* in_sizes, int n_in,
                              void* d_out, int out_size, void* d_ws, size_t ws_size,
                              hipStream_t stream) {
    const float* feat   = (const float*)d_in[0];
    const int*   labels = (const int*)d_in[1];
    float* out = (float*)d_out;

    int*      cnt  = (int*)d_ws;                 // [1024]
    int*      offs = cnt + 1024;                 // [1024]
    int*      rank = offs + 1024;                // [N_ROWS]
    int*      sidx = rank + N_ROWS;              // [N_ROWS]
    float*    mnrm = (float*)(sidx + N_ROWS);    // [C*D]
    unsigned* minb = (unsigned*)(mnrm + C * D);  // [1]
    unsigned* done = minb + 1;                   // [1]

    hipMemsetAsync(cnt, 0, 1024 * sizeof(int), stream);
    k_rank<<<(N_ROWS + 255) / 256, 256, 0, stream>>>(labels, cnt, rank);
    k_scan<<<1, 1024, 0, stream>>>(cnt, offs, minb, done);
    k_scatter<<<(N_ROWS + 255) / 256, 256, 0, stream>>>(labels, rank, offs, sidx);
    k_classsum<<<C, 1024, 0, stream>>>(feat, sidx, offs, cnt, mnrm);
    k_mindist<<<NPAIR, 256, 0, stream>>>(mnrm, minb, done, out);
}